// Round 3
// baseline (1409.606 us; speedup 1.0000x reference)
//
#include <hip/hip_runtime.h>

// ---------------------------------------------------------------------------
// Swin block on MI355X: LN1 -> window QKV GEMM -> windowed MHA -> proj+resid
//                       -> LN2 -> FC1+GELU -> FC2+resid
// GEMMs: bf16 MFMA 16x16x32, 128x128 tile, BK=32, global_load_lds staging
// with pre-swizzled source + swizzled ds_read. Workspace-adaptive chunking:
// QKV/attn chunked over window groups, MLP chunked over row groups, with
// buffer aliasing (A: ln1/attn/ln2 out; B: qkv / fc1 activations).
// ---------------------------------------------------------------------------

typedef unsigned short u16;
typedef unsigned int u32;
typedef __attribute__((ext_vector_type(4))) float f32x4;
typedef __attribute__((ext_vector_type(8))) __bf16 bf16x8;

#define DIMC 768
#define HEADS 12
#define WIN2 196
#define MLP_H 3072
#define MW 39200      // 200 windows * 196
#define MWPAD 39296   // 307 * 128
#define HW_ROWS 39312 // max over chunk tiers of (chunk_start + padded_rows)
#define MM 32768      // 8 * 4096

__device__ __forceinline__ u16 f2bf(float f) {
  u32 u = __float_as_uint(f);
  u32 r = (u + 0x7fffu + ((u >> 16) & 1u)) >> 16;
  return (u16)r;
}

__device__ __forceinline__ f32x4 mfma16(bf16x8 a, bf16x8 b, f32x4 c) {
  return __builtin_amdgcn_mfma_f32_16x16x32_bf16(a, b, c, 0, 0, 0);
}

__device__ __forceinline__ void gload_lds16(const u16* g, u16* l) {
  __builtin_amdgcn_global_load_lds((__attribute__((address_space(1))) void*)g,
                                   (__attribute__((address_space(3))) void*)l,
                                   16, 0, 0);
}

// ---------------- weight fp32 -> bf16 ----------------
__global__ __launch_bounds__(256) void cvt_bf16(const float* __restrict__ s,
                                                u16* __restrict__ d, int n) {
  for (int i = blockIdx.x * 256 + threadIdx.x; i < n; i += gridDim.x * 256)
    d[i] = f2bf(s[i]);
}

// ---------------- LN1 fused with window partition ----------------
__global__ __launch_bounds__(256) void ln1_win_kernel(const float* __restrict__ x,
    const float* __restrict__ g, const float* __restrict__ bb,
    u16* __restrict__ hw) {
  int row = blockIdx.x;
  int t = threadIdx.x;
  const float* src = nullptr;
  if (row < MW) {
    int w = row / WIN2, p = row % WIN2;
    int b = w / 25, wi = w % 25;
    int wy = wi / 5, wx = wi % 5;
    int yy = wy * 14 + p / 14, xx = wx * 14 + p % 14;
    if (yy < 64 && xx < 64) src = x + ((size_t)b * 4096 + (size_t)yy * 64 + xx) * DIMC;
  }
  u16* dst = hw + (size_t)row * DIMC;
  if (src == nullptr) {  // pad token (or M-pad row): zeros (uniform per block)
    for (int i = t; i < DIMC; i += 256) dst[i] = 0;
    return;
  }
  float v0 = src[t], v1 = src[t + 256], v2 = src[t + 512];
  __shared__ float red[8];
  float s = v0 + v1 + v2;
#pragma unroll
  for (int o = 32; o >= 1; o >>= 1) s += __shfl_xor(s, o);
  if ((t & 63) == 0) red[t >> 6] = s;
  __syncthreads();
  float mean = (red[0] + red[1] + red[2] + red[3]) * (1.0f / 768.0f);
  float d0 = v0 - mean, d1 = v1 - mean, d2 = v2 - mean;
  float q = d0 * d0 + d1 * d1 + d2 * d2;
#pragma unroll
  for (int o = 32; o >= 1; o >>= 1) q += __shfl_xor(q, o);
  if ((t & 63) == 0) red[4 + (t >> 6)] = q;
  __syncthreads();
  float var = (red[4] + red[5] + red[6] + red[7]) * (1.0f / 768.0f);
  float rstd = rsqrtf(var + 1e-5f);
  dst[t]       = f2bf(d0 * rstd * g[t]       + bb[t]);
  dst[t + 256] = f2bf(d1 * rstd * g[t + 256] + bb[t + 256]);
  dst[t + 512] = f2bf(d2 * rstd * g[t + 512] + bb[t + 512]);
}

// ---------------- plain LN (for LN2) ----------------
__global__ __launch_bounds__(256) void ln_kernel(const float* __restrict__ x,
    const float* __restrict__ g, const float* __restrict__ bb,
    u16* __restrict__ out) {
  int row = blockIdx.x;
  int t = threadIdx.x;
  const float* src = x + (size_t)row * DIMC;
  u16* dst = out + (size_t)row * DIMC;
  float v0 = src[t], v1 = src[t + 256], v2 = src[t + 512];
  __shared__ float red[8];
  float s = v0 + v1 + v2;
#pragma unroll
  for (int o = 32; o >= 1; o >>= 1) s += __shfl_xor(s, o);
  if ((t & 63) == 0) red[t >> 6] = s;
  __syncthreads();
  float mean = (red[0] + red[1] + red[2] + red[3]) * (1.0f / 768.0f);
  float d0 = v0 - mean, d1 = v1 - mean, d2 = v2 - mean;
  float q = d0 * d0 + d1 * d1 + d2 * d2;
#pragma unroll
  for (int o = 32; o >= 1; o >>= 1) q += __shfl_xor(q, o);
  if ((t & 63) == 0) red[4 + (t >> 6)] = q;
  __syncthreads();
  float var = (red[4] + red[5] + red[6] + red[7]) * (1.0f / 768.0f);
  float rstd = rsqrtf(var + 1e-5f);
  dst[t]       = f2bf(d0 * rstd * g[t]       + bb[t]);
  dst[t + 256] = f2bf(d1 * rstd * g[t + 256] + bb[t + 256]);
  dst[t + 512] = f2bf(d2 * rstd * g[t + 512] + bb[t + 512]);
}

// ---------------- GEMM: C[M,N] = A[M,K](bf16) * W[N,K]^T(bf16) + epilogue ----
// EPI 0: +bias -> bf16 out        (QKV; local rows)
// EPI 1: +bias, window-revert scatter, + x residual -> f32 d_out   (PROJ)
// EPI 2: +bias, exact GELU -> bf16 out                              (FC1; local)
// EPI 3: +bias, + resid (aliases outf, both pre-offset) -> f32      (FC2)
template <int EPI>
__global__ __launch_bounds__(256) void gemm_bt(
    const u16* __restrict__ A, const u16* __restrict__ W,
    const float* __restrict__ bias, int K, int N,
    u16* __restrict__ outb, float* __restrict__ outf,
    const float* __restrict__ resid) {
  __shared__ u16 As[128 * 32];
  __shared__ u16 Bs[128 * 32];
  int tid = threadIdx.x, lane = tid & 63, wv = tid >> 6;
  int bm = blockIdx.x, bn = blockIdx.y;
  int wr = wv >> 1, wc = wv & 1;
  const int fq = lane >> 4, fr = lane & 15;

  f32x4 acc[4][4];
#pragma unroll
  for (int m = 0; m < 4; ++m)
#pragma unroll
    for (int n = 0; n < 4; ++n) acc[m][n] = f32x4{0.f, 0.f, 0.f, 0.f};

  int nk = K >> 5;
  for (int kt = 0; kt < nk; ++kt) {
    // stage A,B tiles: swizzled source so linear LDS holds swizzled layout
#pragma unroll
    for (int s2 = 0; s2 < 2; ++s2) {
      int seg = wv * 2 + s2;
      int ci = seg * 64 + lane;
      int rowIn = ci >> 2;
      int kch = (ci & 3) ^ (rowIn & 3);
      const u16* ga = A + (size_t)(bm * 128 + rowIn) * K + kt * 32 + kch * 8;
      gload_lds16(ga, &As[seg * 512]);
      const u16* gb = W + (size_t)(bn * 128 + rowIn) * K + kt * 32 + kch * 8;
      gload_lds16(gb, &Bs[seg * 512]);
    }
    __syncthreads();
    bf16x8 af[4], bfr[4];
#pragma unroll
    for (int m = 0; m < 4; ++m) {
      int row = wr * 64 + m * 16 + fr;
      int kch = fq ^ (row & 3);
      af[m] = *(const bf16x8*)&As[row * 32 + kch * 8];
    }
#pragma unroll
    for (int n = 0; n < 4; ++n) {
      int row = wc * 64 + n * 16 + fr;
      int kch = fq ^ (row & 3);
      bfr[n] = *(const bf16x8*)&Bs[row * 32 + kch * 8];
    }
#pragma unroll
    for (int m = 0; m < 4; ++m)
#pragma unroll
      for (int n = 0; n < 4; ++n)
        acc[m][n] = mfma16(af[m], bfr[n], acc[m][n]);
    __syncthreads();
  }

  // epilogue; C layout: row = fq*4 + j, col = fr (within 16x16 frag)
  float bcol[4];
#pragma unroll
  for (int n = 0; n < 4; ++n) bcol[n] = bias[bn * 128 + wc * 64 + n * 16 + fr];

#pragma unroll
  for (int m = 0; m < 4; ++m) {
#pragma unroll
    for (int j = 0; j < 4; ++j) {
      int row = bm * 128 + wr * 64 + m * 16 + fq * 4 + j;
#pragma unroll
      for (int n = 0; n < 4; ++n) {
        int col = bn * 128 + wc * 64 + n * 16 + fr;
        float v = acc[m][n][j] + bcol[n];
        if constexpr (EPI == 0) {
          outb[(size_t)row * N + col] = f2bf(v);
        } else if constexpr (EPI == 2) {
          v = 0.5f * v * (1.0f + erff(v * 0.70710678118654752f));
          outb[(size_t)row * N + col] = f2bf(v);
        } else if constexpr (EPI == 1) {
          if (row < MW) {
            int w = row / WIN2, p = row % WIN2;
            int b = w / 25, wi = w % 25;
            int yy = (wi / 5) * 14 + p / 14, xx = (wi % 5) * 14 + p % 14;
            if (yy < 64 && xx < 64) {
              size_t o = ((size_t)b * 4096 + (size_t)yy * 64 + xx) * DIMC + col;
              outf[o] = resid[o] + v;
            }
          }
        } else {  // EPI == 3
          size_t o = (size_t)row * DIMC + col;
          outf[o] = resid[o] + v;
        }
      }
    }
  }
}

// ---------------- windowed attention ----------------
// one block = (local window, head); 4 waves; 16-row q-tiles round-robin.
// qkv pointer is chunk-local; aout pre-offset to the chunk's global rows.
#define ATTN_LDS 94208
__global__ __launch_bounds__(256) void attn_kernel(const u16* __restrict__ qkv,
    const float* __restrict__ bias, u16* __restrict__ aout) {
  extern __shared__ char smem[];
  int tid = threadIdx.x, lane = tid & 63, wv = tid >> 6;
  int blk = blockIdx.x;
  int w = blk / HEADS, h = blk % HEADS;
  const size_t rbase = (size_t)w * WIN2;
  char* KsB = smem;                          // 224*128B = 28672
  char* VtB = smem + 28672;                  // 64*512B  = 32768
  char* PsB = smem + 61440 + wv * 8192;      // 16*512B per wave

  // ---- load K rows (d-contig), swizzled within 128B rows ----
  for (int c = tid; c < 1792; c += 256) {
    int row = c >> 3, off = (c & 7) << 4;  // bytes in row
    char* d = KsB + row * 128 + (off ^ ((row & 7) << 4));
    if (row < WIN2) {
      const u16* gp = qkv + (rbase + row) * 2304 + 768 + h * 64 + (off >> 1);
      *(uint4*)d = *(const uint4*)gp;
    } else {
      *(uint4*)d = make_uint4(0u, 0u, 0u, 0u);
    }
  }
  // ---- load V transposed: Vt[d][k], swizzled within 512B rows ----
  for (int c = tid; c < 1792; c += 256) {
    int row = c >> 3, d0 = (c & 7) << 3;
    u16 tmp[8];
    if (row < WIN2) {
      const u16* gp = qkv + (rbase + row) * 2304 + 1536 + h * 64 + d0;
#pragma unroll
      for (int i = 0; i < 8; ++i) tmp[i] = gp[i];
    } else {
#pragma unroll
      for (int i = 0; i < 8; ++i) tmp[i] = 0;
    }
#pragma unroll
    for (int i = 0; i < 8; ++i) {
      int dd = d0 + i;
      int k2 = row << 1;
      *(u16*)(VtB + dd * 512 + (k2 ^ ((dd & 7) << 4))) = tmp[i];
    }
  }
  __syncthreads();

  const int fq = lane >> 4, fr = lane & 15;
  for (int qt = wv; qt < 13; qt += 4) {
    int qrow = qt * 16 + fr;
    if (qrow > 195) qrow = 195;  // clamp pad rows (results discarded)
    const u16* qg = qkv + (rbase + qrow) * 2304 + h * 64 + fq * 8;
    bf16x8 qa0 = *(const bf16x8*)qg;
    bf16x8 qa1 = *(const bf16x8*)(qg + 32);

    f32x4 sacc[14];
#pragma unroll
    for (int ct = 0; ct < 14; ++ct) {
      int krow = ct * 16 + fr;
      const char* kp = KsB + krow * 128;
      bf16x8 kb0 = *(const bf16x8*)(kp + ((fq * 16) ^ ((krow & 7) << 4)));
      bf16x8 kb1 = *(const bf16x8*)(kp + ((64 + fq * 16) ^ ((krow & 7) << 4)));
      f32x4 z = f32x4{0.f, 0.f, 0.f, 0.f};
      z = mfma16(qa0, kb0, z);
      z = mfma16(qa1, kb1, z);
      sacc[ct] = z;
    }

    // scale + rel-pos bias + pad-col mask, then wave-parallel softmax
    int qb = qt * 16 + fq * 4;
    float rs[4];
#pragma unroll
    for (int j = 0; j < 4; ++j) {
      int q = qb + j;
      int qc = q > 195 ? 195 : q;
      const float* bp = bias + ((size_t)h * WIN2 + qc) * WIN2;
      float mx = -1e30f;
#pragma unroll
      for (int ct = 0; ct < 14; ++ct) {
        int kc = ct * 16 + fr;
        float sv = (kc < WIN2) ? sacc[ct][j] * 0.125f + bp[kc] : -1e30f;
        sacc[ct][j] = sv;
        mx = fmaxf(mx, sv);
      }
#pragma unroll
      for (int o = 1; o < 16; o <<= 1) mx = fmaxf(mx, __shfl_xor(mx, o));
      float sum = 0.f;
#pragma unroll
      for (int ct = 0; ct < 14; ++ct) {
        float p = __expf(sacc[ct][j] - mx);
        sacc[ct][j] = p;
        sum += p;
      }
#pragma unroll
      for (int o = 1; o < 16; o <<= 1) sum += __shfl_xor(sum, o);
      rs[j] = sum;
    }

    // write P (unnormalized, bf16) to wave-private LDS in swizzled layout
#pragma unroll
    for (int ct = 0; ct < 14; ++ct) {
#pragma unroll
      for (int j = 0; j < 4; ++j) {
        int r = fq * 4 + j;
        int c2 = (ct * 16 + fr) << 1;
        *(u16*)(PsB + r * 512 + (c2 ^ ((r & 7) << 4))) = f2bf(sacc[ct][j]);
      }
    }
    asm volatile("s_waitcnt lgkmcnt(0)" ::: "memory");
    __builtin_amdgcn_sched_barrier(0);

    // O = P @ V
    f32x4 oacc[4];
#pragma unroll
    for (int dt = 0; dt < 4; ++dt) oacc[dt] = f32x4{0.f, 0.f, 0.f, 0.f};
#pragma unroll
    for (int kt = 0; kt < 7; ++kt) {
      bf16x8 pa =
          *(const bf16x8*)(PsB + fr * 512 + ((kt * 64 + fq * 16) ^ ((fr & 7) << 4)));
#pragma unroll
      for (int dt = 0; dt < 4; ++dt) {
        int vd = dt * 16 + fr;
        bf16x8 vb =
            *(const bf16x8*)(VtB + vd * 512 + ((kt * 64 + fq * 16) ^ ((vd & 7) << 4)));
        oacc[dt] = mfma16(pa, vb, oacc[dt]);
      }
    }

    // write O rows (divide by softmax denom here)
#pragma unroll
    for (int j = 0; j < 4; ++j) {
      int q = qb + j;
      if (q < WIN2) {
        float inv = 1.0f / rs[j];
#pragma unroll
        for (int dt = 0; dt < 4; ++dt) {
          aout[(rbase + q) * DIMC + h * 64 + dt * 16 + fr] = f2bf(oacc[dt][j] * inv);
        }
      }
    }
  }
}

// ---------------------------------------------------------------------------
extern "C" void kernel_launch(void* const* d_in, const int* in_sizes, int n_in,
                              void* d_out, int out_size, void* d_ws, size_t ws_size,
                              hipStream_t stream) {
  const float* x      = (const float*)d_in[0];
  const float* rpb    = (const float*)d_in[1];
  const float* ln1_g  = (const float*)d_in[2];
  const float* ln1_b  = (const float*)d_in[3];
  const float* qkv_w  = (const float*)d_in[4];
  const float* qkv_b  = (const float*)d_in[5];
  const float* proj_w = (const float*)d_in[6];
  const float* proj_b = (const float*)d_in[7];
  const float* ln2_g  = (const float*)d_in[8];
  const float* ln2_b  = (const float*)d_in[9];
  const float* fc1_w  = (const float*)d_in[10];
  const float* fc1_b  = (const float*)d_in[11];
  const float* fc2_w  = (const float*)d_in[12];
  const float* fc2_b  = (const float*)d_in[13];
  float* out = (float*)d_out;

  // ---- workspace layout (adaptive) ----
  char* ws = (char*)d_ws;
  const size_t W_QKV = (size_t)2304 * 768 * 2;   // 3,538,944
  const size_t W_PRJ = (size_t)768 * 768 * 2;    // 1,179,648
  const size_t W_FC1 = (size_t)3072 * 768 * 2;   // 4,718,592
  const size_t W_FC2 = (size_t)768 * 3072 * 2;   // 4,718,592
  const size_t WB = W_QKV + W_PRJ + W_FC1 + W_FC2;  // 14,155,776
  const size_t HWB = (size_t)HW_ROWS * DIMC * 2;    // 60,383,232
  u16* wqkv  = (u16*)ws;
  u16* wproj = (u16*)(ws + W_QKV);
  u16* wfc1  = (u16*)(ws + W_QKV + W_PRJ);
  u16* wfc2  = (u16*)(ws + W_QKV + W_PRJ + W_FC1);
  u16* hw    = (u16*)(ws + WB);        // bufA: ln1-out / attn-out / ln2-out
  u16* bufB  = (u16*)(ws + WB + HWB);  // qkv chunks / fc1-activation chunks

  // pick coarsest chunking that fits ws_size
  int Cq = 0;
  const int cqs[4] = {1, 2, 4, 8};
  for (int t = 0; t < 4; ++t) {
    int cq = cqs[t];
    int rowsW = (200 / cq) * 196;
    size_t pr = (size_t)((rowsW + 127) / 128) * 128;
    size_t q_b = pr * 2304 * 2;
    size_t f_b = (size_t)(MM / cq) * MLP_H * 2;
    size_t bb = q_b > f_b ? q_b : f_b;
    if (WB + HWB + bb <= ws_size) { Cq = cq; break; }
  }
  if (Cq == 0) return;  // ws < ~100MB: cannot run (visible as zero-output)
  const int Cm = Cq;
  const int Wc = 200 / Cq;            // windows per qkv/attn chunk
  const int rowsW = Wc * 196;         // real rows per chunk
  const int padRows = ((rowsW + 127) / 128) * 128;
  const int Rm = MM / Cm;             // MLP rows per chunk

  // ---- weights to bf16 ----
  cvt_bf16<<<2048, 256, 0, stream>>>(qkv_w, wqkv, 2304 * 768);
  cvt_bf16<<<2048, 256, 0, stream>>>(proj_w, wproj, 768 * 768);
  cvt_bf16<<<2048, 256, 0, stream>>>(fc1_w, wfc1, 3072 * 768);
  cvt_bf16<<<2048, 256, 0, stream>>>(fc2_w, wfc2, 768 * 3072);

  // ---- LN1 + window partition (zero-fills all HW_ROWS) ----
  ln1_win_kernel<<<HW_ROWS, 256, 0, stream>>>(x, ln1_g, ln1_b, hw);

  // ---- QKV GEMM + attention, chunked over window groups ----
  hipFuncSetAttribute((const void*)attn_kernel,
                      hipFuncAttributeMaxDynamicSharedMemorySize, ATTN_LDS);
  for (int c = 0; c < Cq; ++c) {
    const u16* Ac = hw + (size_t)c * rowsW * DIMC;
    gemm_bt<0><<<dim3(padRows / 128, 2304 / 128), 256, 0, stream>>>(
        Ac, wqkv, qkv_b, 768, 2304, bufB, nullptr, nullptr);
    // attn overwrites this chunk's hw rows with attention output
    attn_kernel<<<Wc * HEADS, 256, ATTN_LDS, stream>>>(
        bufB, rpb, hw + (size_t)c * rowsW * DIMC);
  }

  // ---- proj GEMM + window revert + residual -> d_out ----
  gemm_bt<1><<<dim3(MWPAD / 128, DIMC / 128), 256, 0, stream>>>(
      hw, wproj, proj_b, 768, DIMC, nullptr, out, x);

  // ---- LN2 (into bufA; attn-out is dead now) ----
  u16* ln2b = hw;
  ln_kernel<<<MM, 256, 0, stream>>>(out, ln2_g, ln2_b, ln2b);

  // ---- MLP, chunked over row groups; fc1 activations in bufB ----
  for (int m = 0; m < Cm; ++m) {
    gemm_bt<2><<<dim3(Rm / 128, MLP_H / 128), 256, 0, stream>>>(
        ln2b + (size_t)m * Rm * DIMC, wfc1, fc1_b, 768, MLP_H,
        bufB, nullptr, nullptr);
    float* outc = out + (size_t)m * Rm * DIMC;
    gemm_bt<3><<<dim3(Rm / 128, DIMC / 128), 256, 0, stream>>>(
        bufB, wfc2, fc2_b, 3072, DIMC, nullptr, outc, outc);
  }
}

// Round 4
// 1278.887 us; speedup vs baseline: 1.1022x; 1.1022x over previous
//
#include <hip/hip_runtime.h>

// ---------------------------------------------------------------------------
// Swin block on MI355X. GEMMs: 256x256 tile, BK=64, 8 waves, 8-phase
// interleaved schedule (T2 swizzle + T3/T4 counted vmcnt + T5 setprio),
// global_load_lds staging with pre-swizzled source. Attn/LN/cvt unchanged
// from the round-3 PASSING kernel.
// ---------------------------------------------------------------------------

typedef unsigned short u16;
typedef unsigned int u32;
typedef __attribute__((ext_vector_type(4))) float f32x4;
typedef __attribute__((ext_vector_type(8))) __bf16 bf16x8;

#define DIMC 768
#define HEADS 12
#define WIN2 196
#define MLP_H 3072
#define MW 39200      // 200 windows * 196
#define MWPAD 39424   // 154 * 256
#define HW_ROWS 39424
#define MM 32768      // 8 * 4096

__device__ __forceinline__ u16 f2bf(float f) {
  u32 u = __float_as_uint(f);
  u32 r = (u + 0x7fffu + ((u >> 16) & 1u)) >> 16;
  return (u16)r;
}

__device__ __forceinline__ f32x4 mfma16(bf16x8 a, bf16x8 b, f32x4 c) {
  return __builtin_amdgcn_mfma_f32_16x16x32_bf16(a, b, c, 0, 0, 0);
}

__device__ __forceinline__ void gload_lds16(const u16* g, u16* l) {
  __builtin_amdgcn_global_load_lds((__attribute__((address_space(1))) void*)g,
                                   (__attribute__((address_space(3))) void*)l,
                                   16, 0, 0);
}

// ---------------- weight fp32 -> bf16 ----------------
__global__ __launch_bounds__(256) void cvt_bf16(const float* __restrict__ s,
                                                u16* __restrict__ d, int n) {
  for (int i = blockIdx.x * 256 + threadIdx.x; i < n; i += gridDim.x * 256)
    d[i] = f2bf(s[i]);
}

// ---------------- LN1 fused with window partition ----------------
__global__ __launch_bounds__(256) void ln1_win_kernel(const float* __restrict__ x,
    const float* __restrict__ g, const float* __restrict__ bb,
    u16* __restrict__ hw) {
  int row = blockIdx.x;
  int t = threadIdx.x;
  const float* src = nullptr;
  if (row < MW) {
    int w = row / WIN2, p = row % WIN2;
    int b = w / 25, wi = w % 25;
    int wy = wi / 5, wx = wi % 5;
    int yy = wy * 14 + p / 14, xx = wx * 14 + p % 14;
    if (yy < 64 && xx < 64) src = x + ((size_t)b * 4096 + (size_t)yy * 64 + xx) * DIMC;
  }
  u16* dst = hw + (size_t)row * DIMC;
  if (src == nullptr) {
    for (int i = t; i < DIMC; i += 256) dst[i] = 0;
    return;
  }
  float v0 = src[t], v1 = src[t + 256], v2 = src[t + 512];
  __shared__ float red[8];
  float s = v0 + v1 + v2;
#pragma unroll
  for (int o = 32; o >= 1; o >>= 1) s += __shfl_xor(s, o);
  if ((t & 63) == 0) red[t >> 6] = s;
  __syncthreads();
  float mean = (red[0] + red[1] + red[2] + red[3]) * (1.0f / 768.0f);
  float d0 = v0 - mean, d1 = v1 - mean, d2 = v2 - mean;
  float q = d0 * d0 + d1 * d1 + d2 * d2;
#pragma unroll
  for (int o = 32; o >= 1; o >>= 1) q += __shfl_xor(q, o);
  if ((t & 63) == 0) red[4 + (t >> 6)] = q;
  __syncthreads();
  float var = (red[4] + red[5] + red[6] + red[7]) * (1.0f / 768.0f);
  float rstd = rsqrtf(var + 1e-5f);
  dst[t]       = f2bf(d0 * rstd * g[t]       + bb[t]);
  dst[t + 256] = f2bf(d1 * rstd * g[t + 256] + bb[t + 256]);
  dst[t + 512] = f2bf(d2 * rstd * g[t + 512] + bb[t + 512]);
}

// ---------------- plain LN (for LN2) ----------------
__global__ __launch_bounds__(256) void ln_kernel(const float* __restrict__ x,
    const float* __restrict__ g, const float* __restrict__ bb,
    u16* __restrict__ out) {
  int row = blockIdx.x;
  int t = threadIdx.x;
  const float* src = x + (size_t)row * DIMC;
  u16* dst = out + (size_t)row * DIMC;
  float v0 = src[t], v1 = src[t + 256], v2 = src[t + 512];
  __shared__ float red[8];
  float s = v0 + v1 + v2;
#pragma unroll
  for (int o = 32; o >= 1; o >>= 1) s += __shfl_xor(s, o);
  if ((t & 63) == 0) red[t >> 6] = s;
  __syncthreads();
  float mean = (red[0] + red[1] + red[2] + red[3]) * (1.0f / 768.0f);
  float d0 = v0 - mean, d1 = v1 - mean, d2 = v2 - mean;
  float q = d0 * d0 + d1 * d1 + d2 * d2;
#pragma unroll
  for (int o = 32; o >= 1; o >>= 1) q += __shfl_xor(q, o);
  if ((t & 63) == 0) red[4 + (t >> 6)] = q;
  __syncthreads();
  float var = (red[4] + red[5] + red[6] + red[7]) * (1.0f / 768.0f);
  float rstd = rsqrtf(var + 1e-5f);
  dst[t]       = f2bf(d0 * rstd * g[t]       + bb[t]);
  dst[t + 256] = f2bf(d1 * rstd * g[t + 256] + bb[t + 256]);
  dst[t + 512] = f2bf(d2 * rstd * g[t + 512] + bb[t + 512]);
}

// ---------------- 256x256 8-phase GEMM ----------------
// LDS (dynamic 128KB): [dbuf][A|B][256 rows][64 bf16]. Row = 128B.
// Swizzle: 16B-chunk index c3 = logical ^ (row&7)  (conflict-free 2-way reads).
// Half-tiles: A-h = rows {h*64..+63} u {128+h*64..+63};
//             B-h = rows {q*64+h*32..+31, q=0..3}  (match per-phase consumption).
// Schedule per tile T (phases ph0..ph3), dbufC=buf[T&1], dbufO=buf[(T+1)&1]:
//  boundary: vmcnt(6) [or 0 for last tile]; barrier
//  ph0: read A-h0 + B-h0 (dbufC); stage (T+1,A-h1)->dbufO; lgkm0; 16 MFMA q00; bar
//  ph1: read B-h1;               stage (T+2,A-h0)->dbufC; lgkm0; 16 MFMA q01; bar
//  ph2: read A-h1;               stage (T+2,B-h0)->dbufC; lgkm0; 16 MFMA q11; bar
//  ph3: (b0 kept in regs);       stage (T+2,B-h1)->dbufC;        16 MFMA q10
// vmcnt(6) = 3 half-tiles (2 loads/wave each) in flight. All region hazards
// audited: each stage target's last reader finished >=1 barrier earlier.
__device__ __forceinline__ void stageA8(const u16* __restrict__ G, int K,
    int rowBase, int tile, u16* ldsM, int h, int wv, int lane) {
#pragma unroll
  for (int i = 0; i < 2; ++i) {
    int o = (i * 8 + wv) * 8;
    int rb = h * 64 + ((o < 64) ? o : (o + 64));
    int r = rb + (lane >> 3);
    int lc = (lane & 7) ^ (r & 7);
    const u16* g = G + (size_t)(rowBase + r) * K + tile * 64 + lc * 8;
    gload_lds16(g, ldsM + rb * 64);
  }
}
__device__ __forceinline__ void stageB8(const u16* __restrict__ G, int K,
    int rowBase, int tile, u16* ldsM, int h, int wv, int lane) {
#pragma unroll
  for (int i = 0; i < 2; ++i) {
    int o = (i * 8 + wv) * 8;
    int rb = (o >> 5) * 64 + h * 32 + (o & 31);
    int r = rb + (lane >> 3);
    int lc = (lane & 7) ^ (r & 7);
    const u16* g = G + (size_t)(rowBase + r) * K + tile * 64 + lc * 8;
    gload_lds16(g, ldsM + rb * 64);
  }
}
__device__ __forceinline__ void readA8(const u16* lA, int wrM, int mh,
    int fq, int fr, bf16x8 a[4][2]) {
#pragma unroll
  for (int mf2 = 0; mf2 < 4; ++mf2) {
    int rt = wrM * 128 + mh * 64 + mf2 * 16 + fr;
#pragma unroll
    for (int kk = 0; kk < 2; ++kk) {
      int c3 = (kk * 4 + fq) ^ (rt & 7);
      a[mf2][kk] = *(const bf16x8*)(lA + rt * 64 + c3 * 8);
    }
  }
}
__device__ __forceinline__ void readB8(const u16* lB, int wcN, int nh,
    int fq, int fr, bf16x8 b[2][2]) {
#pragma unroll
  for (int nf2 = 0; nf2 < 2; ++nf2) {
    int rt = wcN * 64 + nh * 32 + nf2 * 16 + fr;
#pragma unroll
    for (int kk = 0; kk < 2; ++kk) {
      int c3 = (kk * 4 + fq) ^ (rt & 7);
      b[nf2][kk] = *(const bf16x8*)(lB + rt * 64 + c3 * 8);
    }
  }
}

#define MFMA_Q(MH, NH, AR, BR)                                             \
  _Pragma("unroll") for (int mf2 = 0; mf2 < 4; ++mf2)                      \
  _Pragma("unroll") for (int nf2 = 0; nf2 < 2; ++nf2)                      \
  _Pragma("unroll") for (int kk = 0; kk < 2; ++kk)                         \
    acc[(MH)*4 + mf2][(NH)*2 + nf2] =                                      \
        mfma16(AR[mf2][kk], BR[nf2][kk], acc[(MH)*4 + mf2][(NH)*2 + nf2]);

template <int EPI>
__global__ __launch_bounds__(512, 2) void gemm8(
    const u16* __restrict__ A, const u16* __restrict__ W,
    const float* __restrict__ bias, int K, int N,
    u16* __restrict__ outb, float* __restrict__ outf,
    const float* __restrict__ resid) {
  extern __shared__ u16 lds[];  // 131072 bytes
  int tid = threadIdx.x, lane = tid & 63, wv = tid >> 6;
  int bm = blockIdx.x, bn = blockIdx.y;
  int wrM = wv >> 2, wcN = wv & 3;
  int fq = lane >> 4, fr = lane & 15;
  int rowBase = bm * 256, colBase = bn * 256;
  int nk = K >> 6;

  f32x4 acc[8][4];
#pragma unroll
  for (int i = 0; i < 8; ++i)
#pragma unroll
    for (int j = 0; j < 4; ++j) acc[i][j] = f32x4{0.f, 0.f, 0.f, 0.f};

  u16* A0d = lds;
  u16* B0d = lds + 16384;
  u16* A1d = lds + 32768;
  u16* B1d = lds + 49152;

  // prologue: tile0 {Ah0,Bh0,Bh1,Ah1}(oldest 4) then tile1 {Ah0,Bh0,Bh1}
  stageA8(A, K, rowBase, 0, A0d, 0, wv, lane);
  stageB8(W, K, colBase, 0, B0d, 0, wv, lane);
  stageB8(W, K, colBase, 0, B0d, 1, wv, lane);
  stageA8(A, K, rowBase, 0, A0d, 1, wv, lane);
  stageA8(A, K, rowBase, 1, A1d, 0, wv, lane);
  stageB8(W, K, colBase, 1, B1d, 0, wv, lane);
  stageB8(W, K, colBase, 1, B1d, 1, wv, lane);

  bf16x8 a[4][2], b0[2][2], b1[2][2];

  for (int T = 0; T < nk; ++T) {
    u16* lA = lds + (T & 1) * 32768;
    u16* lB = lA + 16384;
    u16* lAo = lds + ((T + 1) & 1) * 32768;

    if (T == nk - 1) { asm volatile("s_waitcnt vmcnt(0)" ::: "memory"); }
    else             { asm volatile("s_waitcnt vmcnt(6)" ::: "memory"); }
    __builtin_amdgcn_s_barrier();
    __builtin_amdgcn_sched_barrier(0);

    // ---- ph0: q(0,0) ----
    readA8(lA, wrM, 0, fq, fr, a);
    readB8(lB, wcN, 0, fq, fr, b0);
    if (T + 1 < nk) stageA8(A, K, rowBase, T + 1, lAo, 1, wv, lane);
    asm volatile("s_waitcnt lgkmcnt(0)" ::: "memory");
    __builtin_amdgcn_sched_barrier(0);
    __builtin_amdgcn_s_setprio(1);
    MFMA_Q(0, 0, a, b0)
    __builtin_amdgcn_s_setprio(0);
    __builtin_amdgcn_s_barrier();

    // ---- ph1: q(0,1) ----
    readB8(lB, wcN, 1, fq, fr, b1);
    if (T + 2 < nk) stageA8(A, K, rowBase, T + 2, lA, 0, wv, lane);
    asm volatile("s_waitcnt lgkmcnt(0)" ::: "memory");
    __builtin_amdgcn_sched_barrier(0);
    __builtin_amdgcn_s_setprio(1);
    MFMA_Q(0, 1, a, b1)
    __builtin_amdgcn_s_setprio(0);
    __builtin_amdgcn_s_barrier();

    // ---- ph2: q(1,1) ----
    readA8(lA, wrM, 1, fq, fr, a);
    if (T + 2 < nk) stageB8(W, K, colBase, T + 2, lB, 0, wv, lane);
    asm volatile("s_waitcnt lgkmcnt(0)" ::: "memory");
    __builtin_amdgcn_sched_barrier(0);
    __builtin_amdgcn_s_setprio(1);
    MFMA_Q(1, 1, a, b1)
    __builtin_amdgcn_s_setprio(0);
    __builtin_amdgcn_s_barrier();

    // ---- ph3: q(1,0)  (b0 held in registers since ph0) ----
    if (T + 2 < nk) stageB8(W, K, colBase, T + 2, lB, 1, wv, lane);
    __builtin_amdgcn_s_setprio(1);
    MFMA_Q(1, 0, a, b0)
    __builtin_amdgcn_s_setprio(0);
    // boundary vmcnt+barrier at top of next iteration
  }

  // epilogue; within 16x16 frag: row offset = fq*4+j (A side), col = fr (W side)
  float bcol[4];
#pragma unroll
  for (int nf = 0; nf < 4; ++nf)
    bcol[nf] = bias[colBase + wcN * 64 + nf * 16 + fr];

#pragma unroll
  for (int mf = 0; mf < 8; ++mf) {
#pragma unroll
    for (int j = 0; j < 4; ++j) {
      int row = rowBase + wrM * 128 + mf * 16 + fq * 4 + j;
#pragma unroll
      for (int nf = 0; nf < 4; ++nf) {
        int col = colBase + wcN * 64 + nf * 16 + fr;
        float v = acc[mf][nf][j] + bcol[nf];
        if constexpr (EPI == 0) {
          outb[(size_t)row * N + col] = f2bf(v);
        } else if constexpr (EPI == 2) {
          v = 0.5f * v * (1.0f + erff(v * 0.70710678118654752f));
          outb[(size_t)row * N + col] = f2bf(v);
        } else if constexpr (EPI == 1) {
          if (row < MW) {
            int w = row / WIN2, p = row % WIN2;
            int b = w / 25, wi = w % 25;
            int yy = (wi / 5) * 14 + p / 14, xx = (wi % 5) * 14 + p % 14;
            if (yy < 64 && xx < 64) {
              size_t o = ((size_t)b * 4096 + (size_t)yy * 64 + xx) * DIMC + col;
              outf[o] = resid[o] + v;
            }
          }
        } else {  // EPI == 3
          size_t o = (size_t)row * DIMC + col;
          outf[o] = resid[o] + v;
        }
      }
    }
  }
}

// ---------------- windowed attention (unchanged, round-3 verified) ----------
#define ATTN_LDS 94208
__global__ __launch_bounds__(256) void attn_kernel(const u16* __restrict__ qkv,
    const float* __restrict__ bias, u16* __restrict__ aout) {
  extern __shared__ char smem[];
  int tid = threadIdx.x, lane = tid & 63, wv = tid >> 6;
  int blk = blockIdx.x;
  int w = blk / HEADS, h = blk % HEADS;
  const size_t rbase = (size_t)w * WIN2;
  char* KsB = smem;
  char* VtB = smem + 28672;
  char* PsB = smem + 61440 + wv * 8192;

  for (int c = tid; c < 1792; c += 256) {
    int row = c >> 3, off = (c & 7) << 4;
    char* d = KsB + row * 128 + (off ^ ((row & 7) << 4));
    if (row < WIN2) {
      const u16* gp = qkv + (rbase + row) * 2304 + 768 + h * 64 + (off >> 1);
      *(uint4*)d = *(const uint4*)gp;
    } else {
      *(uint4*)d = make_uint4(0u, 0u, 0u, 0u);
    }
  }
  for (int c = tid; c < 1792; c += 256) {
    int row = c >> 3, d0 = (c & 7) << 3;
    u16 tmp[8];
    if (row < WIN2) {
      const u16* gp = qkv + (rbase + row) * 2304 + 1536 + h * 64 + d0;
#pragma unroll
      for (int i = 0; i < 8; ++i) tmp[i] = gp[i];
    } else {
#pragma unroll
      for (int i = 0; i < 8; ++i) tmp[i] = 0;
    }
#pragma unroll
    for (int i = 0; i < 8; ++i) {
      int dd = d0 + i;
      int k2 = row << 1;
      *(u16*)(VtB + dd * 512 + (k2 ^ ((dd & 7) << 4))) = tmp[i];
    }
  }
  __syncthreads();

  const int fq = lane >> 4, fr = lane & 15;
  for (int qt = wv; qt < 13; qt += 4) {
    int qrow = qt * 16 + fr;
    if (qrow > 195) qrow = 195;
    const u16* qg = qkv + (rbase + qrow) * 2304 + h * 64 + fq * 8;
    bf16x8 qa0 = *(const bf16x8*)qg;
    bf16x8 qa1 = *(const bf16x8*)(qg + 32);

    f32x4 sacc[14];
#pragma unroll
    for (int ct = 0; ct < 14; ++ct) {
      int krow = ct * 16 + fr;
      const char* kp = KsB + krow * 128;
      bf16x8 kb0 = *(const bf16x8*)(kp + ((fq * 16) ^ ((krow & 7) << 4)));
      bf16x8 kb1 = *(const bf16x8*)(kp + ((64 + fq * 16) ^ ((krow & 7) << 4)));
      f32x4 z = f32x4{0.f, 0.f, 0.f, 0.f};
      z = mfma16(qa0, kb0, z);
      z = mfma16(qa1, kb1, z);
      sacc[ct] = z;
    }

    int qb = qt * 16 + fq * 4;
    float rs[4];
#pragma unroll
    for (int j = 0; j < 4; ++j) {
      int q = qb + j;
      int qc = q > 195 ? 195 : q;
      const float* bp = bias + ((size_t)h * WIN2 + qc) * WIN2;
      float mx = -1e30f;
#pragma unroll
      for (int ct = 0; ct < 14; ++ct) {
        int kc = ct * 16 + fr;
        float sv = (kc < WIN2) ? sacc[ct][j] * 0.125f + bp[kc] : -1e30f;
        sacc[ct][j] = sv;
        mx = fmaxf(mx, sv);
      }
#pragma unroll
      for (int o = 1; o < 16; o <<= 1) mx = fmaxf(mx, __shfl_xor(mx, o));
      float sum = 0.f;
#pragma unroll
      for (int ct = 0; ct < 14; ++ct) {
        float p = __expf(sacc[ct][j] - mx);
        sacc[ct][j] = p;
        sum += p;
      }
#pragma unroll
      for (int o = 1; o < 16; o <<= 1) sum += __shfl_xor(sum, o);
      rs[j] = sum;
    }

#pragma unroll
    for (int ct = 0; ct < 14; ++ct) {
#pragma unroll
      for (int j = 0; j < 4; ++j) {
        int r = fq * 4 + j;
        int c2 = (ct * 16 + fr) << 1;
        *(u16*)(PsB + r * 512 + (c2 ^ ((r & 7) << 4))) = f2bf(sacc[ct][j]);
      }
    }
    asm volatile("s_waitcnt lgkmcnt(0)" ::: "memory");
    __builtin_amdgcn_sched_barrier(0);

    f32x4 oacc[4];
#pragma unroll
    for (int dt = 0; dt < 4; ++dt) oacc[dt] = f32x4{0.f, 0.f, 0.f, 0.f};
#pragma unroll
    for (int kt = 0; kt < 7; ++kt) {
      bf16x8 pa =
          *(const bf16x8*)(PsB + fr * 512 + ((kt * 64 + fq * 16) ^ ((fr & 7) << 4)));
#pragma unroll
      for (int dt = 0; dt < 4; ++dt) {
        int vd = dt * 16 + fr;
        bf16x8 vb =
            *(const bf16x8*)(VtB + vd * 512 + ((kt * 64 + fq * 16) ^ ((vd & 7) << 4)));
        oacc[dt] = mfma16(pa, vb, oacc[dt]);
      }
    }

#pragma unroll
    for (int j = 0; j < 4; ++j) {
      int q = qb + j;
      if (q < WIN2) {
        float inv = 1.0f / rs[j];
#pragma unroll
        for (int dt = 0; dt < 4; ++dt) {
          aout[(rbase + q) * DIMC + h * 64 + dt * 16 + fr] = f2bf(oacc[dt][j] * inv);
        }
      }
    }
  }
}

// ---------------------------------------------------------------------------
extern "C" void kernel_launch(void* const* d_in, const int* in_sizes, int n_in,
                              void* d_out, int out_size, void* d_ws, size_t ws_size,
                              hipStream_t stream) {
  const float* x      = (const float*)d_in[0];
  const float* rpb    = (const float*)d_in[1];
  const float* ln1_g  = (const float*)d_in[2];
  const float* ln1_b  = (const float*)d_in[3];
  const float* qkv_w  = (const float*)d_in[4];
  const float* qkv_b  = (const float*)d_in[5];
  const float* proj_w = (const float*)d_in[6];
  const float* proj_b = (const float*)d_in[7];
  const float* ln2_g  = (const float*)d_in[8];
  const float* ln2_b  = (const float*)d_in[9];
  const float* fc1_w  = (const float*)d_in[10];
  const float* fc1_b  = (const float*)d_in[11];
  const float* fc2_w  = (const float*)d_in[12];
  const float* fc2_b  = (const float*)d_in[13];
  float* out = (float*)d_out;

  char* ws = (char*)d_ws;
  const size_t W_QKV = (size_t)2304 * 768 * 2;
  const size_t W_PRJ = (size_t)768 * 768 * 2;
  const size_t W_FC1 = (size_t)3072 * 768 * 2;
  const size_t W_FC2 = (size_t)768 * 3072 * 2;
  const size_t WB = W_QKV + W_PRJ + W_FC1 + W_FC2;
  const size_t HWB = (size_t)HW_ROWS * DIMC * 2;
  u16* wqkv  = (u16*)ws;
  u16* wproj = (u16*)(ws + W_QKV);
  u16* wfc1  = (u16*)(ws + W_QKV + W_PRJ);
  u16* wfc2  = (u16*)(ws + W_QKV + W_PRJ + W_FC1);
  u16* hw    = (u16*)(ws + WB);
  u16* bufB  = (u16*)(ws + WB + HWB);

  // coarsest chunking that fits (padded rows now 256-multiples)
  int Cq = 0;
  const int cqs[4] = {1, 2, 4, 8};
  for (int t = 0; t < 4; ++t) {
    int cq = cqs[t];
    int rw = (200 / cq) * 196;
    size_t pr = (size_t)((rw + 255) / 256) * 256;
    size_t q_b = pr * 2304 * 2;
    size_t f_b = (size_t)(MM / cq) * MLP_H * 2;
    size_t bb = q_b > f_b ? q_b : f_b;
    if (WB + HWB + bb <= ws_size) { Cq = cq; break; }
  }
  if (Cq == 0) return;
  const int Cm = Cq;
  const int Wc = 200 / Cq;
  const int rowsW = Wc * 196;
  const int padRows = ((rowsW + 255) / 256) * 256;
  const int Rm = MM / Cm;

  cvt_bf16<<<2048, 256, 0, stream>>>(qkv_w, wqkv, 2304 * 768);
  cvt_bf16<<<2048, 256, 0, stream>>>(proj_w, wproj, 768 * 768);
  cvt_bf16<<<2048, 256, 0, stream>>>(fc1_w, wfc1, 3072 * 768);
  cvt_bf16<<<2048, 256, 0, stream>>>(fc2_w, wfc2, 768 * 3072);

  ln1_win_kernel<<<HW_ROWS, 256, 0, stream>>>(x, ln1_g, ln1_b, hw);

  hipFuncSetAttribute((const void*)gemm8<0>,
                      hipFuncAttributeMaxDynamicSharedMemorySize, 131072);
  hipFuncSetAttribute((const void*)gemm8<1>,
                      hipFuncAttributeMaxDynamicSharedMemorySize, 131072);
  hipFuncSetAttribute((const void*)gemm8<2>,
                      hipFuncAttributeMaxDynamicSharedMemorySize, 131072);
  hipFuncSetAttribute((const void*)gemm8<3>,
                      hipFuncAttributeMaxDynamicSharedMemorySize, 131072);
  hipFuncSetAttribute((const void*)attn_kernel,
                      hipFuncAttributeMaxDynamicSharedMemorySize, ATTN_LDS);

  for (int c = 0; c < Cq; ++c) {
    const u16* Ac = hw + (size_t)c * rowsW * DIMC;
    gemm8<0><<<dim3(padRows / 256, 2304 / 256), 512, 131072, stream>>>(
        Ac, wqkv, qkv_b, 768, 2304, bufB, nullptr, nullptr);
    attn_kernel<<<Wc * HEADS, 256, ATTN_LDS, stream>>>(
        bufB, rpb, hw + (size_t)c * rowsW * DIMC);
  }

  gemm8<1><<<dim3(MWPAD / 256, DIMC / 256), 512, 131072, stream>>>(
      hw, wproj, proj_b, 768, DIMC, nullptr, out, x);

  u16* ln2b = hw;
  ln_kernel<<<MM, 256, 0, stream>>>(out, ln2_g, ln2_b, ln2b);

  for (int m = 0; m < Cm; ++m) {
    gemm8<2><<<dim3(Rm / 256, MLP_H / 256), 512, 131072, stream>>>(
        ln2b + (size_t)m * Rm * DIMC, wfc1, fc1_b, 768, MLP_H,
        bufB, nullptr, nullptr);
    float* outc = out + (size_t)m * Rm * DIMC;
    gemm8<3><<<dim3(Rm / 256, DIMC / 256), 512, 131072, stream>>>(
        bufB, wfc2, fc2_b, 3072, DIMC, nullptr, outc, outc);
  }
}